// Round 8
// baseline (333.881 us; speedup 1.0000x reference)
//
#include <hip/hip_runtime.h>

#define GRIDW 48
#define NNODES 147456
#define NTILES 2304   // NNODES/64
#define GB 512        // persistent GEMM grid
#define NSH 8         // stat shadow copies (XCD-indexed)
#define SHS 128       // shadow stride (floats)

typedef __attribute__((ext_vector_type(8))) short short8;
typedef __attribute__((ext_vector_type(4))) float f32x4;

__device__ inline unsigned short f2bf(float f) {
    union { float f; unsigned u; } v; v.f = f;
    unsigned r = v.u + 0x7FFFu + ((v.u >> 16) & 1u);
    return (unsigned short)(r >> 16);
}
__device__ inline float bf2f(unsigned short h) {
    union { unsigned u; float f; } v; v.u = ((unsigned)h) << 16;
    return v.f;
}

// ---------------------------------------------------------------------------
// prep: weights->bf16 [col][KP] (k-contig, zero-padded), padded biases,
// zero stat shadows (re-zeroed every graph replay -> atomic accum safe).
// wt2 is 176 cols: [g2(132) | w2(44)].
// ---------------------------------------------------------------------------
__global__ void prep(const float* __restrict__ w0, const float* __restrict__ b0,
                     const float* __restrict__ w1, const float* __restrict__ b1,
                     const float* __restrict__ g2, const float* __restrict__ w2,
                     const float* __restrict__ b2, const float* __restrict__ w3,
                     const float* __restrict__ b3,
                     unsigned short* __restrict__ wt0, unsigned short* __restrict__ wt1,
                     unsigned short* __restrict__ wt2, unsigned short* __restrict__ wt3,
                     float* __restrict__ biasf0, float* __restrict__ biasf1,
                     float* __restrict__ biasf2, float* __restrict__ biasf3,
                     float* __restrict__ statz) {
    int id = blockIdx.x * 256 + threadIdx.x;
    if (id < 14336) {                         // wt0: 112 cols x 128 k
        int col = id >> 7, k = id & 127;
        wt0[id] = (col < 102) ? f2bf(w0[k * 102 + col]) : (unsigned short)0;
    } else if (id < 24576) {                  // wt1: 80 x 128
        int e = id - 14336; int col = e >> 7, k = e & 127;
        wt1[e] = (col < 73 && k < 102) ? f2bf(w1[k * 73 + col]) : (unsigned short)0;
    } else if (id < 41472) {                  // wt2: 176 x 96 (g2 | w2)
        int e = id - 24576; int col = e / 96, k = e - (e / 96) * 96;
        unsigned short v = 0;
        if (k < 73) v = (col < 132) ? f2bf(g2[k * 132 + col]) : f2bf(w2[k * 44 + (col - 132)]);
        wt2[e] = v;
    } else if (id < 42496) {                  // wt3: 16 x 64
        int e = id - 41472; int col = e >> 6, k = e & 63;
        wt3[e] = (k < 44) ? f2bf(w3[k * 16 + col]) : (unsigned short)0;
    } else if (id < 42608) { int c = id - 42496; biasf0[c] = (c < 102) ? b0[c] : 0.f; }
    else if (id < 42688) { int c = id - 42608; biasf1[c] = (c < 73) ? b1[c] : 0.f; }
    else if (id < 42864) { int c = id - 42688; biasf2[c] = (c < 132) ? 0.f : b2[c - 132]; }
    else if (id < 42880) { int c = id - 42864; biasf3[c] = b3[c]; }
    else if (id < 49024) { statz[id - 42880] = 0.f; }   // 6 x 1024 stat shadows
}

// ---------------------------------------------------------------------------
// Persistent MFMA GEMM: whole-K in LDS, 64-row tiles grid-strided,
// double-buffered A with register prefetch, BN of the previous layer applied
// on the A side during LDS commit. STATS: per-block reduction -> atomicAdd
// into 8 XCD-indexed shadow copies. OUTCM (round 17): channel-major output
// Yout[col][row] — packs the 4 consecutive-row accumulators into one uint2
// store (feeds the coalesced stencil).
// ---------------------------------------------------------------------------
template<int K, int KP, int MP, int MOUT, int PREVM, int BNSRC,
         bool STATS, bool OUTBF, bool ABF16, bool OUTCM>
__global__ __launch_bounds__(256) void gemm_p(
    const void* __restrict__ Ain, const unsigned short* __restrict__ WT,
    const float* __restrict__ biasf,
    const float* __restrict__ q0, const float* __restrict__ q1,
    const float* __restrict__ q2, const float* __restrict__ q3,
    float invN, void* __restrict__ Yout,
    float* __restrict__ sumO, float* __restrict__ ssO)
{
    constexpr int KS = KP + 8;
    constexpr int NCF = MP / 16;
    constexpr int UPR = ABF16 ? (K / 8) : (K / 4);
    constexpr int TOT = 64 * UPR;
    constexpr int NLD = (TOT + 255) / 256;
    __shared__ __align__(16) unsigned short As[2][64 * KS];
    __shared__ __align__(16) unsigned short Bs[MP * KS];
    __shared__ float bnA[KP], bnB[KP];

    const int tid = threadIdx.x;
    const int lane = tid & 63, wv = tid >> 6, qd = lane >> 4, lc = lane & 15;

    if (BNSRC == 1) {
        if (tid < KP) {
            float a = 0.f, b = 0.f;
            if (tid < PREVM) {
                float s0 = 0.f, s1 = 0.f;
#pragma unroll
                for (int sh = 0; sh < NSH; ++sh) {
                    s0 += q0[sh * SHS + tid];
                    s1 += q1[sh * SHS + tid];
                }
                float m = s0 * invN;
                float v = s1 * invN - m * m;
                float sc = q2[tid] * rsqrtf(v + 1e-5f);
                a = sc; b = q3[tid] - m * sc;
            }
            bnA[tid] = a; bnB[tid] = b;
        }
    }
    for (int g = tid; g < MP * (KP / 8); g += 256) {
        int col = g / (KP / 8), u = g - col * (KP / 8);
        *(uint4*)&Bs[col * KS + u * 8] = *(const uint4*)&WT[(size_t)col * KP + u * 8];
    }
    if constexpr (KP > K) {
        constexpr int PADU = (KP - K) / 2;
        for (int g = tid; g < 64 * PADU; g += 256) {
            int row = g / PADU, u = g - row * PADU;
            *(unsigned*)&As[0][row * KS + K + u * 2] = 0u;
            *(unsigned*)&As[1][row * KS + K + u * 2] = 0u;
        }
    }

    float bvr[NCF];
#pragma unroll
    for (int cf = 0; cf < NCF; ++cf) bvr[cf] = biasf[cf * 16 + lc];

    float cs[NCF], cq[NCF];
    if (STATS) {
#pragma unroll
        for (int cf = 0; cf < NCF; ++cf) { cs[cf] = 0.f; cq[cf] = 0.f; }
    }

    uint4 pfb[NLD];
    float4 pff[NLD];

    int t = blockIdx.x;
#pragma unroll
    for (int i = 0; i < NLD; ++i) {
        int g = tid + 256 * i;
        if (g < TOT) {
            if constexpr (ABF16)
                pfb[i] = *(const uint4*)((const unsigned short*)Ain + (size_t)t * 64 * K + g * 8);
            else
                pff[i] = *(const float4*)((const float*)Ain + (size_t)t * 64 * K + g * 4);
        }
    }
    __syncthreads();

    int buf = 0;
    for (; t < NTILES; t += GB) {
#pragma unroll
        for (int i = 0; i < NLD; ++i) {
            int g = tid + 256 * i;
            if (g < TOT) {
                int row = g / UPR, u = g - row * UPR;
                if constexpr (ABF16) {
                    uint4 w = pfb[i];
                    if (BNSRC != 0) {
                        unsigned* wp = (unsigned*)&w;
#pragma unroll
                        for (int pp = 0; pp < 4; ++pp) {
                            int kk = u * 8 + 2 * pp;
                            float lo = bf2f((unsigned short)(wp[pp] & 0xFFFFu)) * bnA[kk] + bnB[kk];
                            float hi = bf2f((unsigned short)(wp[pp] >> 16)) * bnA[kk + 1] + bnB[kk + 1];
                            wp[pp] = (unsigned)f2bf(lo) | ((unsigned)f2bf(hi) << 16);
                        }
                    }
                    *(uint4*)&As[buf][row * KS + u * 8] = w;
                } else {
                    float4 v = pff[i];
                    if (BNSRC != 0) {
                        int kk = u * 4;
                        v.x = v.x * bnA[kk] + bnB[kk];
                        v.y = v.y * bnA[kk + 1] + bnB[kk + 1];
                        v.z = v.z * bnA[kk + 2] + bnB[kk + 2];
                        v.w = v.w * bnA[kk + 3] + bnB[kk + 3];
                    }
                    unsigned lo = (unsigned)f2bf(v.x) | ((unsigned)f2bf(v.y) << 16);
                    unsigned hi = (unsigned)f2bf(v.z) | ((unsigned)f2bf(v.w) << 16);
                    *(uint2*)&As[buf][row * KS + u * 4] = make_uint2(lo, hi);
                }
            }
        }
        int t2 = t + GB;
        if (t2 < NTILES) {
#pragma unroll
            for (int i = 0; i < NLD; ++i) {
                int g = tid + 256 * i;
                if (g < TOT) {
                    if constexpr (ABF16)
                        pfb[i] = *(const uint4*)((const unsigned short*)Ain + (size_t)t2 * 64 * K + g * 8);
                    else
                        pff[i] = *(const float4*)((const float*)Ain + (size_t)t2 * 64 * K + g * 4);
                }
            }
        }
        __syncthreads();

        f32x4 acc[NCF];
#pragma unroll
        for (int cf = 0; cf < NCF; ++cf) acc[cf] = (f32x4){0.f, 0.f, 0.f, 0.f};
#pragma unroll
        for (int kt = 0; kt < KP / 32; ++kt) {
            const int kb = kt * 32 + qd * 8;
            short8 a = *(const short8*)&As[buf][(wv * 16 + lc) * KS + kb];
#pragma unroll
            for (int cf = 0; cf < NCF; ++cf) {
                short8 b = *(const short8*)&Bs[(cf * 16 + lc) * KS + kb];
                acc[cf] = __builtin_amdgcn_mfma_f32_16x16x32_bf16(a, b, acc[cf], 0, 0, 0);
            }
        }
#pragma unroll
        for (int cf = 0; cf < NCF; ++cf) {
            const int col = cf * 16 + lc;
            const float bv = bvr[cf];
            if constexpr (OUTCM) {
                // channel-major: 4 consecutive rows -> one uint2
                const int row0 = t * 64 + wv * 16 + qd * 4;
                unsigned lo = (unsigned)f2bf(acc[cf][0] + bv)
                            | ((unsigned)f2bf(acc[cf][1] + bv) << 16);
                unsigned hi = (unsigned)f2bf(acc[cf][2] + bv)
                            | ((unsigned)f2bf(acc[cf][3] + bv) << 16);
                *(uint2*)((unsigned short*)Yout + (size_t)col * NNODES + row0) =
                    make_uint2(lo, hi);
            } else {
#pragma unroll
                for (int rr = 0; rr < 4; ++rr) {
                    float v = acc[cf][rr] + bv;
                    int row = t * 64 + wv * 16 + qd * 4 + rr;
                    if (OUTBF) ((unsigned short*)Yout)[(size_t)row * MP + col] = f2bf(v);
                    else       ((float*)Yout)[(size_t)row * MP + col] = v;
                    if (STATS) { cs[cf] += v; cq[cf] += v * v; }
                }
            }
        }
        buf ^= 1;
    }

    if (STATS) {
        __syncthreads();
        float* red = (float*)As;
        float* redq = red + 4 * MP;
#pragma unroll
        for (int cf = 0; cf < NCF; ++cf) {
            float s = cs[cf], qq = cq[cf];
            s += __shfl_down(s, 32, 64); s += __shfl_down(s, 16, 64);
            qq += __shfl_down(qq, 32, 64); qq += __shfl_down(qq, 16, 64);
            if (lane < 16) {
                red[wv * MP + cf * 16 + lane] = s;
                redq[wv * MP + cf * 16 + lane] = qq;
            }
        }
        __syncthreads();
        if (tid < MOUT) {
            float s = red[tid] + red[MP + tid] + red[2 * MP + tid] + red[3 * MP + tid];
            float qq = redq[tid] + redq[MP + tid] + redq[2 * MP + tid] + redq[3 * MP + tid];
            const int sh = blockIdx.x & (NSH - 1);      // XCD-indexed shadow
            atomicAdd(&sumO[sh * SHS + tid], s);
            atomicAdd(&ssO[sh * SHS + tid], qq);
        }
    }
}

// ---------------------------------------------------------------------------
// Separable GMM stencil (round 17): COALESCED, channel-major input.
// TR2[c][node] planes; thread = one node, wave = 64 consecutive nodes ->
// every load is a contiguous 128B wave access (~2 TA cyc vs 64 for the old
// 352B-stride gathers; the r12-r15 46us invariant was TA address-divergence:
// 33 waves/CU x 48 loads x 64 cyc = 42us). Borders via exact 0/1 weight
// masks + clamped offsets (bit-identical math, r15 fold order). Output
// staged in LDS Ctile then written out fully contiguous. Stats from a
// coalesced Ctile pass (352 LDS atomics/block; r16's 13M was its killer).
// Blocks never straddle batches (2304 = 9 x 256).
// ---------------------------------------------------------------------------
__global__ __launch_bounds__(256) void gmm_stencil(
    const unsigned short* __restrict__ TR2, unsigned short* __restrict__ C,
    const float* __restrict__ mu, const float* __restrict__ sigma,
    float* __restrict__ sum2, float* __restrict__ ss2)
{
    constexpr int CT = 56;   // Ctile stride (shorts); 112B keeps uint4 16B-aligned
    __shared__ __align__(16) unsigned short Ctile[256 * CT];   // 28KB
    __shared__ float gxs[3][3], gys[3][3];   // [d][k]
    __shared__ float red[88];
    const int tid = threadIdx.x;
    if (tid < 88) red[tid] = 0.f;
    if (tid < 18) {
        int d = (tid / 3) % 3, k = tid % 3;
        bool isy = tid >= 9;
        float e = 0.5f * (float)(d - 1) + 0.5f;
        float mm = mu[k * 2 + (isy ? 1 : 0)];
        float sg = sigma[k * 2 + (isy ? 1 : 0)];
        float v = expf(-0.5f * (e - mm) * (e - mm) / (1e-15f + sg * sg));
        if (isy) gys[d][k] = v; else gxs[d][k] = v;
    }
    __syncthreads();

    // bijective XCD-chunked mapping: 576 = 8 x 72 contiguous per XCD
    const int wg = blockIdx.x;
    const int gb = (wg & 7) * 72 + (wg >> 3);
    const int node0 = gb << 8;                  // 256 nodes per block
    const int node = node0 + tid;
    const int iy  = node % 48;
    const int ixg = (node / 48) % 48;

    const int eym = (iy > 0) ? 1 : 0;
    const int eyp = (iy < GRIDW - 1) ? 1 : 0;
    const float my0 = (iy > 0) ? 1.f : 0.f;
    const float my2 = (iy < GRIDW - 1) ? 1.f : 0.f;
    const int dxm = (ixg > 0) ? 48 : 0;
    const int dxp = (ixg < GRIDW - 1) ? 48 : 0;
    const float wxm = (ixg > 0) ? 1.f : 0.f;
    const float wxp = (ixg < GRIDW - 1) ? 1.f : 0.f;
    const int nx = 1 + (ixg > 0) + (ixg < GRIDW - 1);
    const int ny = 1 + (iy > 0) + (iy < GRIDW - 1);
    const float inv = 1.f / (float)(nx * ny);

    // coefficients -> registers; y-weights folded with exact 0/1 masks
    float gxr[3][3], wym[3], wyc[3], wyp[3];
#pragma unroll
    for (int k = 0; k < 3; ++k) {
        gxr[0][k] = gxs[0][k]; gxr[1][k] = gxs[1][k]; gxr[2][k] = gxs[2][k];
        wym[k] = my0 * gys[0][k];
        wyc[k] = gys[1][k];
        wyp[k] = my2 * gys[2][k];
    }

#pragma unroll 1
    for (int og = 0; og < 11; ++og) {
        const int c0 = og * 4;
        const size_t pb = (size_t)c0 * NNODES;
        f32x4 o = (f32x4){0.f, 0.f, 0.f, 0.f};

#define COLU(U, CB, WX)                                                        \
        f32x4 U;                                                               \
        {                                                                      \
            const int cb_ = (CB);                                              \
            _Pragma("unroll")                                                  \
            for (int j = 0; j < 4; ++j) {                                      \
                const unsigned short* pl =                                     \
                    TR2 + pb + (size_t)(k * 44 + j) * NNODES;                  \
                float vm = bf2f(pl[cb_ - eym]);                                \
                float vc = bf2f(pl[cb_]);                                      \
                float vp = bf2f(pl[cb_ + eyp]);                                \
                U[j] = ((WX) * wym[k]) * vm + ((WX) * wyc[k]) * vc             \
                     + ((WX) * wyp[k]) * vp;                                   \
            }                                                                  \
        }

#pragma unroll
        for (int k = 0; k < 3; ++k) {
            COLU(uL, node - dxm, wxm)
            COLU(uC, node,       1.f)
            COLU(uR, node + dxp, wxp)
            o += gxr[0][k] * uL + gxr[1][k] * uC + gxr[2][k] * uR;
        }
#undef COLU

        o = o * inv;
        const unsigned short* rp = TR2 + (size_t)(132 + c0) * NNODES;
        o.x += bf2f(rp[node]);
        o.y += bf2f(rp[NNODES + node]);
        o.z += bf2f(rp[2 * (size_t)NNODES + node]);
        o.w += bf2f(rp[3 * (size_t)NNODES + node]);

        unsigned lo = (unsigned)f2bf(o.x) | ((unsigned)f2bf(o.y) << 16);
        unsigned hi = (unsigned)f2bf(o.z) | ((unsigned)f2bf(o.w) << 16);
        *(uint2*)&Ctile[tid * CT + c0] = make_uint2(lo, hi);
    }
    *(uint2*)&Ctile[tid * CT + 44] = make_uint2(0u, 0u);   // pad cols 44..47
    __syncthreads();

    // stats from Ctile (bf16-rounded values; self-consistent with what L3
    // consumes) — coalesced-ish b16 reads, one LDS atomic per wave-channel
    {
        const int lane = tid & 63, w4 = tid >> 6;
        if (lane < 44) {
            float s = 0.f, q = 0.f;
            const int nb = w4 * 64;
            for (int n = nb; n < nb + 64; ++n) {
                float v = bf2f(Ctile[n * CT + lane]);
                s += v; q += v * v;
            }
            atomicAdd(&red[lane], s);
            atomicAdd(&red[44 + lane], q);
        }
    }
    // fully contiguous write-out: 24KB per block
    for (int g = tid; g < 1536; g += 256) {
        int n = g / 6, part = g - n * 6;
        *(uint4*)&C[(size_t)(node0 + n) * 48 + part * 8] =
            *(const uint4*)&Ctile[n * CT + part * 8];
    }
    __syncthreads();
    if (tid < 88) {
        const int sh = wg & (NSH - 1);
        if (tid < 44) atomicAdd(&sum2[sh * SHS + tid], red[tid]);
        else          atomicAdd(&ss2[sh * SHS + tid - 44], red[tid]);
    }
}

// ---------------------------------------------------------------------------
extern "C" void kernel_launch(void* const* d_in, const int* in_sizes, int n_in,
                              void* d_out, int out_size, void* d_ws, size_t ws_size,
                              hipStream_t stream) {
    const float* x      = (const float*)d_in[0];
    const float* w0     = (const float*)d_in[3];
    const float* b0     = (const float*)d_in[4];
    const float* gamma0 = (const float*)d_in[5];
    const float* beta0  = (const float*)d_in[6];
    const float* w1     = (const float*)d_in[7];
    const float* b1     = (const float*)d_in[8];
    const float* gamma1 = (const float*)d_in[9];
    const float* beta1  = (const float*)d_in[10];
    const float* w2     = (const float*)d_in[11];
    const float* g2     = (const float*)d_in[12];
    const float* mu2    = (const float*)d_in[13];
    const float* sigma2 = (const float*)d_in[14];
    const float* b2     = (const float*)d_in[15];
    const float* gamma2 = (const float*)d_in[16];
    const float* beta2  = (const float*)d_in[17];
    const float* w3     = (const float*)d_in[18];
    const float* b3     = (const float*)d_in[19];
    float* out = (float*)d_out;

    const int N = NNODES;
    const float invN = 1.0f / (float)N;

    // [0,44N): Y1 bf16 (40N f-eq) then C bf16 48 cols (24N f-eq) — disjoint
    // [44N,132N): Y0 bf16 (56N f-eq) then TR2 channel-major 176 planes — disjoint
    const size_t tailOff = (size_t)N * 132;
    size_t need = (tailOff + 300000) * sizeof(float);
    if (ws_size < need) return;

    float* ws = (float*)d_ws;
    unsigned short* bufY1 = (unsigned short*)ws;
    unsigned short* bufC  = (unsigned short*)ws;
    unsigned short* bufY0 = (unsigned short*)(ws + (size_t)N * 44);
    unsigned short* bufTR = bufY0;

    float* tail = ws + tailOff;
    // 6 stat arrays x 8 shadows x 128 stride = 6144 floats
    float* sum0 = tail;                 // 1024
    float* ss0  = tail + 1024;          // 1024
    float* sum1 = tail + 2048;          // 1024
    float* ss1  = tail + 3072;          // 1024
    float* sum2 = tail + 4096;          // 1024
    float* ss2  = tail + 5120;          // 1024
    float* biasf0 = tail + 6144;        // 112
    float* biasf1 = tail + 6256;        // 80
    float* biasf2 = tail + 6336;        // 176
    float* biasf3 = tail + 6512;        // 16
    unsigned short* wt0 = (unsigned short*)(tail + 6528);   // 112*128
    unsigned short* wt1 = wt0 + 14336;                      // 80*128
    unsigned short* wt2 = wt1 + 10240;                      // 176*96
    unsigned short* wt3 = wt2 + 16896;                      // 16*64

    // prep re-zeros the stat shadows each replay (graph-safe).
    prep<<<192, 256, 0, stream>>>(w0, b0, w1, b1, g2, w2, b2, w3, b3,
                                  wt0, wt1, wt2, wt3,
                                  biasf0, biasf1, biasf2, biasf3, tail);

    // L0: Y0 = x @ w0 + b0 (bf16 out, stats -> sum0/ss0 shadows)
    gemm_p<128, 128, 112, 102, 0, 0, true, true, false, false><<<GB, 256, 0, stream>>>(
        x, wt0, biasf0, nullptr, nullptr, nullptr, nullptr, invN, bufY0, sum0, ss0);

    // L1: Y1 = BN0(Y0) @ w1 + b1 (BN on A-side; stats -> sum1/ss1 shadows)
    gemm_p<112, 128, 80, 73, 102, 1, true, true, true, false><<<GB, 256, 0, stream>>>(
        bufY0, wt1, biasf1, sum0, ss0, gamma0, beta0, invN, bufY1, sum1, ss1);

    // L2: TR2 = BN1(Y1) @ [g2 | w2] (+[0|b2]), 176 wide, CHANNEL-MAJOR out
    gemm_p<80, 96, 176, 176, 73, 1, false, true, true, true><<<GB, 256, 0, stream>>>(
        bufY1, wt2, biasf2, sum1, ss1, gamma1, beta1, invN, bufTR, nullptr, nullptr);

    // coalesced channel-major stencil: C(bf16,48) = r + agg(t)/deg
    gmm_stencil<<<576, 256, 0, stream>>>(bufTR, bufC, mu2, sigma2, sum2, ss2);

    // L3: out = BN2(C) @ w3 + b3 (fp32 out; BN fold from shadow sums)
    gemm_p<48, 64, 16, 16, 44, 1, false, false, true, false><<<GB, 256, 0, stream>>>(
        bufC, wt3, biasf3, sum2, ss2, gamma2, beta2, invN, out, nullptr, nullptr);
}

// Round 9
// 264.063 us; speedup vs baseline: 1.2644x; 1.2644x over previous
//
#include <hip/hip_runtime.h>

#define GRIDW 48
#define NNODES 147456
#define NTILES 2304   // NNODES/64
#define GB 512        // persistent GEMM grid
#define NSH 8         // stat shadow copies (XCD-indexed)
#define SHS 128       // shadow stride (floats)

typedef __attribute__((ext_vector_type(8))) short short8;
typedef __attribute__((ext_vector_type(4))) float f32x4;

__device__ inline unsigned short f2bf(float f) {
    union { float f; unsigned u; } v; v.f = f;
    unsigned r = v.u + 0x7FFFu + ((v.u >> 16) & 1u);
    return (unsigned short)(r >> 16);
}
__device__ inline float bf2f(unsigned short h) {
    union { unsigned u; float f; } v; v.u = ((unsigned)h) << 16;
    return v.f;
}
__device__ __forceinline__ f32x4 b2v(uint2 v) {
    f32x4 r;
    r.x = bf2f((unsigned short)(v.x & 0xFFFFu));
    r.y = bf2f((unsigned short)(v.x >> 16));
    r.z = bf2f((unsigned short)(v.y & 0xFFFFu));
    r.w = bf2f((unsigned short)(v.y >> 16));
    return r;
}

// ---------------------------------------------------------------------------
// prep: weights->bf16 [col][KP] (k-contig, zero-padded), padded biases,
// zero stat shadows (re-zeroed every graph replay -> atomic accum safe).
// wt2 is 176 cols: [g2(132) | w2(44)].
// ---------------------------------------------------------------------------
__global__ void prep(const float* __restrict__ w0, const float* __restrict__ b0,
                     const float* __restrict__ w1, const float* __restrict__ b1,
                     const float* __restrict__ g2, const float* __restrict__ w2,
                     const float* __restrict__ b2, const float* __restrict__ w3,
                     const float* __restrict__ b3,
                     unsigned short* __restrict__ wt0, unsigned short* __restrict__ wt1,
                     unsigned short* __restrict__ wt2, unsigned short* __restrict__ wt3,
                     float* __restrict__ biasf0, float* __restrict__ biasf1,
                     float* __restrict__ biasf2, float* __restrict__ biasf3,
                     float* __restrict__ statz) {
    int id = blockIdx.x * 256 + threadIdx.x;
    if (id < 14336) {                         // wt0: 112 cols x 128 k
        int col = id >> 7, k = id & 127;
        wt0[id] = (col < 102) ? f2bf(w0[k * 102 + col]) : (unsigned short)0;
    } else if (id < 24576) {                  // wt1: 80 x 128
        int e = id - 14336; int col = e >> 7, k = e & 127;
        wt1[e] = (col < 73 && k < 102) ? f2bf(w1[k * 73 + col]) : (unsigned short)0;
    } else if (id < 41472) {                  // wt2: 176 x 96 (g2 | w2)
        int e = id - 24576; int col = e / 96, k = e - (e / 96) * 96;
        unsigned short v = 0;
        if (k < 73) v = (col < 132) ? f2bf(g2[k * 132 + col]) : f2bf(w2[k * 44 + (col - 132)]);
        wt2[e] = v;
    } else if (id < 42496) {                  // wt3: 16 x 64
        int e = id - 41472; int col = e >> 6, k = e & 63;
        wt3[e] = (k < 44) ? f2bf(w3[k * 16 + col]) : (unsigned short)0;
    } else if (id < 42608) { int c = id - 42496; biasf0[c] = (c < 102) ? b0[c] : 0.f; }
    else if (id < 42688) { int c = id - 42608; biasf1[c] = (c < 73) ? b1[c] : 0.f; }
    else if (id < 42864) { int c = id - 42688; biasf2[c] = (c < 132) ? 0.f : b2[c - 132]; }
    else if (id < 42880) { int c = id - 42864; biasf3[c] = b3[c]; }
    else if (id < 49024) { statz[id - 42880] = 0.f; }   // 6 x 1024 stat shadows
}

// ---------------------------------------------------------------------------
// Persistent MFMA GEMM: whole-K in LDS, 64-row tiles grid-strided,
// double-buffered A with register prefetch, BN on the A side during LDS
// commit. STATS -> 8 XCD-indexed shadow copies. OUTCM: channel-major output
// (L2). ACM (round 18): channel-major A input (L3 reads the stencil's C2
// planes; LDS transpose during commit; c>=PREVM guard replaces pad-zeroing).
// ---------------------------------------------------------------------------
template<int K, int KP, int MP, int MOUT, int PREVM, int BNSRC,
         bool STATS, bool OUTBF, bool ABF16, bool OUTCM, bool ACM>
__global__ __launch_bounds__(256) void gemm_p(
    const void* __restrict__ Ain, const unsigned short* __restrict__ WT,
    const float* __restrict__ biasf,
    const float* __restrict__ q0, const float* __restrict__ q1,
    const float* __restrict__ q2, const float* __restrict__ q3,
    float invN, void* __restrict__ Yout,
    float* __restrict__ sumO, float* __restrict__ ssO)
{
    constexpr int KS = KP + 8;
    constexpr int NCF = MP / 16;
    constexpr int UPR = ABF16 ? (K / 8) : (K / 4);
    constexpr int TOT = ACM ? (K * 16) : (64 * UPR);
    constexpr int NLD = (TOT + 255) / 256;
    __shared__ __align__(16) unsigned short As[2][64 * KS];
    __shared__ __align__(16) unsigned short Bs[MP * KS];
    __shared__ float bnA[KP], bnB[KP];

    const int tid = threadIdx.x;
    const int lane = tid & 63, wv = tid >> 6, qd = lane >> 4, lc = lane & 15;

    if (BNSRC == 1) {
        if (tid < KP) {
            float a = 0.f, b = 0.f;
            if (tid < PREVM) {
                float s0 = 0.f, s1 = 0.f;
#pragma unroll
                for (int sh = 0; sh < NSH; ++sh) {
                    s0 += q0[sh * SHS + tid];
                    s1 += q1[sh * SHS + tid];
                }
                float m = s0 * invN;
                float v = s1 * invN - m * m;
                float sc = q2[tid] * rsqrtf(v + 1e-5f);
                a = sc; b = q3[tid] - m * sc;
            }
            bnA[tid] = a; bnB[tid] = b;
        }
    }
    for (int g = tid; g < MP * (KP / 8); g += 256) {
        int col = g / (KP / 8), u = g - col * (KP / 8);
        *(uint4*)&Bs[col * KS + u * 8] = *(const uint4*)&WT[(size_t)col * KP + u * 8];
    }
    if constexpr (KP > K) {
        constexpr int PADU = (KP - K) / 2;
        for (int g = tid; g < 64 * PADU; g += 256) {
            int row = g / PADU, u = g - row * PADU;
            *(unsigned*)&As[0][row * KS + K + u * 2] = 0u;
            *(unsigned*)&As[1][row * KS + K + u * 2] = 0u;
        }
    }

    float bvr[NCF];
#pragma unroll
    for (int cf = 0; cf < NCF; ++cf) bvr[cf] = biasf[cf * 16 + lc];

    float cs[NCF], cq[NCF];
    if (STATS) {
#pragma unroll
        for (int cf = 0; cf < NCF; ++cf) { cs[cf] = 0.f; cq[cf] = 0.f; }
    }

    uint4 pfb[NLD];
    float4 pff[NLD];
    uint2 pfa[NLD];

    int t = blockIdx.x;
#pragma unroll
    for (int i = 0; i < NLD; ++i) {
        int g = tid + 256 * i;
        if (g < TOT) {
            if constexpr (ACM) {
                int c = g >> 4, r4 = g & 15;
                pfa[i] = *(const uint2*)((const unsigned short*)Ain
                          + (size_t)c * NNODES + (size_t)t * 64 + r4 * 4);
            } else if constexpr (ABF16) {
                pfb[i] = *(const uint4*)((const unsigned short*)Ain + (size_t)t * 64 * K + g * 8);
            } else {
                pff[i] = *(const float4*)((const float*)Ain + (size_t)t * 64 * K + g * 4);
            }
        }
    }
    __syncthreads();

    int buf = 0;
    for (; t < NTILES; t += GB) {
#pragma unroll
        for (int i = 0; i < NLD; ++i) {
            int g = tid + 256 * i;
            if (g < TOT) {
                if constexpr (ACM) {
                    int c = g >> 4, r4 = g & 15;
                    uint2 w = pfa[i];
                    unsigned short h0 = (unsigned short)(w.x & 0xFFFFu);
                    unsigned short h1 = (unsigned short)(w.x >> 16);
                    unsigned short h2 = (unsigned short)(w.y & 0xFFFFu);
                    unsigned short h3 = (unsigned short)(w.y >> 16);
                    float v0 = 0.f, v1 = 0.f, v2 = 0.f, v3 = 0.f;
                    if (c < PREVM) {
                        float a = bnA[c], bb = bnB[c];
                        v0 = bf2f(h0) * a + bb; v1 = bf2f(h1) * a + bb;
                        v2 = bf2f(h2) * a + bb; v3 = bf2f(h3) * a + bb;
                    }
                    As[buf][(r4 * 4 + 0) * KS + c] = f2bf(v0);
                    As[buf][(r4 * 4 + 1) * KS + c] = f2bf(v1);
                    As[buf][(r4 * 4 + 2) * KS + c] = f2bf(v2);
                    As[buf][(r4 * 4 + 3) * KS + c] = f2bf(v3);
                } else if constexpr (ABF16) {
                    int row = g / UPR, u = g - row * UPR;
                    uint4 w = pfb[i];
                    if (BNSRC != 0) {
                        unsigned* wp = (unsigned*)&w;
#pragma unroll
                        for (int pp = 0; pp < 4; ++pp) {
                            int kk = u * 8 + 2 * pp;
                            float lo = bf2f((unsigned short)(wp[pp] & 0xFFFFu)) * bnA[kk] + bnB[kk];
                            float hi = bf2f((unsigned short)(wp[pp] >> 16)) * bnA[kk + 1] + bnB[kk + 1];
                            wp[pp] = (unsigned)f2bf(lo) | ((unsigned)f2bf(hi) << 16);
                        }
                    }
                    *(uint4*)&As[buf][row * KS + u * 8] = w;
                } else {
                    int row = g / UPR, u = g - row * UPR;
                    float4 v = pff[i];
                    if (BNSRC != 0) {
                        int kk = u * 4;
                        v.x = v.x * bnA[kk] + bnB[kk];
                        v.y = v.y * bnA[kk + 1] + bnB[kk + 1];
                        v.z = v.z * bnA[kk + 2] + bnB[kk + 2];
                        v.w = v.w * bnA[kk + 3] + bnB[kk + 3];
                    }
                    unsigned lo = (unsigned)f2bf(v.x) | ((unsigned)f2bf(v.y) << 16);
                    unsigned hi = (unsigned)f2bf(v.z) | ((unsigned)f2bf(v.w) << 16);
                    *(uint2*)&As[buf][row * KS + u * 4] = make_uint2(lo, hi);
                }
            }
        }
        int t2 = t + GB;
        if (t2 < NTILES) {
#pragma unroll
            for (int i = 0; i < NLD; ++i) {
                int g = tid + 256 * i;
                if (g < TOT) {
                    if constexpr (ACM) {
                        int c = g >> 4, r4 = g & 15;
                        pfa[i] = *(const uint2*)((const unsigned short*)Ain
                                  + (size_t)c * NNODES + (size_t)t2 * 64 + r4 * 4);
                    } else if constexpr (ABF16) {
                        pfb[i] = *(const uint4*)((const unsigned short*)Ain + (size_t)t2 * 64 * K + g * 8);
                    } else {
                        pff[i] = *(const float4*)((const float*)Ain + (size_t)t2 * 64 * K + g * 4);
                    }
                }
            }
        }
        __syncthreads();

        f32x4 acc[NCF];
#pragma unroll
        for (int cf = 0; cf < NCF; ++cf) acc[cf] = (f32x4){0.f, 0.f, 0.f, 0.f};
#pragma unroll
        for (int kt = 0; kt < KP / 32; ++kt) {
            const int kb = kt * 32 + qd * 8;
            short8 a = *(const short8*)&As[buf][(wv * 16 + lc) * KS + kb];
#pragma unroll
            for (int cf = 0; cf < NCF; ++cf) {
                short8 b = *(const short8*)&Bs[(cf * 16 + lc) * KS + kb];
                acc[cf] = __builtin_amdgcn_mfma_f32_16x16x32_bf16(a, b, acc[cf], 0, 0, 0);
            }
        }
#pragma unroll
        for (int cf = 0; cf < NCF; ++cf) {
            const int col = cf * 16 + lc;
            const float bv = bvr[cf];
            if constexpr (OUTCM) {
                // channel-major: 4 consecutive rows -> one uint2
                const int row0 = t * 64 + wv * 16 + qd * 4;
                unsigned lo = (unsigned)f2bf(acc[cf][0] + bv)
                            | ((unsigned)f2bf(acc[cf][1] + bv) << 16);
                unsigned hi = (unsigned)f2bf(acc[cf][2] + bv)
                            | ((unsigned)f2bf(acc[cf][3] + bv) << 16);
                *(uint2*)((unsigned short*)Yout + (size_t)col * NNODES + row0) =
                    make_uint2(lo, hi);
            } else {
#pragma unroll
                for (int rr = 0; rr < 4; ++rr) {
                    float v = acc[cf][rr] + bv;
                    int row = t * 64 + wv * 16 + qd * 4 + rr;
                    if (OUTBF) ((unsigned short*)Yout)[(size_t)row * MP + col] = f2bf(v);
                    else       ((float*)Yout)[(size_t)row * MP + col] = v;
                    if (STATS) { cs[cf] += v; cq[cf] += v * v; }
                }
            }
        }
        buf ^= 1;
    }

    if (STATS) {
        __syncthreads();
        float* red = (float*)As;
        float* redq = red + 4 * MP;
#pragma unroll
        for (int cf = 0; cf < NCF; ++cf) {
            float s = cs[cf], qq = cq[cf];
            s += __shfl_down(s, 32, 64); s += __shfl_down(s, 16, 64);
            qq += __shfl_down(qq, 32, 64); qq += __shfl_down(qq, 16, 64);
            if (lane < 16) {
                red[wv * MP + cf * 16 + lane] = s;
                redq[wv * MP + cf * 16 + lane] = qq;
            }
        }
        __syncthreads();
        if (tid < MOUT) {
            float s = red[tid] + red[MP + tid] + red[2 * MP + tid] + red[3 * MP + tid];
            float qq = redq[tid] + redq[MP + tid] + redq[2 * MP + tid] + redq[3 * MP + tid];
            const int sh = blockIdx.x & (NSH - 1);      // XCD-indexed shadow
            atomicAdd(&sumO[sh * SHS + tid], s);
            atomicAdd(&ssO[sh * SHS + tid], qq);
        }
    }
}

// ---------------------------------------------------------------------------
// Separable GMM stencil (round 18): channel-major, y-VECTORIZED.
// Thread = (og, 4 consecutive y-nodes). Per (plane, x-col): 3 uint2 shifted
// window loads give y-1/y/y+1 vectors for 4 outputs -> 116 coalesced loads
// per thread (vs r17's 1232 scalar: instruction-issue-bound at 134us; vs
// r12-15's 48 scattered: TA-bound at 46us). og is wave-uniform (og-major
// task order); borders via per-element 0/1 mask weights + clamped addrs
// (same products as r17, which passed). Output channel-major C2 (coalesced);
// stats via wave-shuffle reduce + 8 atomics/wave into XCD shadows.
// ---------------------------------------------------------------------------
__global__ __launch_bounds__(256) void gmm_stencil(
    const unsigned short* __restrict__ TR2, unsigned short* __restrict__ C2,
    const float* __restrict__ mu, const float* __restrict__ sigma,
    float* __restrict__ sum2, float* __restrict__ ss2)
{
    __shared__ float gxs[3][3], gys[3][3];   // [d][k]
    const int tid = threadIdx.x;
    if (tid < 18) {
        int d = (tid / 3) % 3, k = tid % 3;
        bool isy = tid >= 9;
        float e = 0.5f * (float)(d - 1) + 0.5f;
        float mm = mu[k * 2 + (isy ? 1 : 0)];
        float sg = sigma[k * 2 + (isy ? 1 : 0)];
        float v = expf(-0.5f * (e - mm) * (e - mm) / (1e-15f + sg * sg));
        if (isy) gys[d][k] = v; else gxs[d][k] = v;
    }
    __syncthreads();

    // bijective XCD-chunked mapping: 1584 = 8 x 198; og-major task order
    const int wg  = blockIdx.x;
    const int gbT = (wg & 7) * 198 + (wg >> 3);
    const int task0 = gbT * 256;                 // block never straddles og
    const int og  = task0 / 36864;               // wave-uniform
    const int n4i = (task0 % 36864) + tid;       // node4-group index
    const int node4 = n4i * 4;
    const int c0 = og * 4;

    const int y0  = node4 % 48;                  // in {0,4,...,44}
    const int ixg = (node4 / 48) % 48;

    // masks / clamps (garbage lanes are weight-masked to exact 0)
    const float m0 = (y0 > 0) ? 1.f : 0.f;       // element 0 y-minus mask
    const float m3 = (y0 < 44) ? 1.f : 0.f;      // element 3 y-plus mask
    const int dA = (y0 > 0) ? 4 : 0;
    const int dC = (y0 < 44) ? 4 : 0;
    const float wxm = (ixg > 0) ? 1.f : 0.f;
    const float wxp = (ixg < GRIDW - 1) ? 1.f : 0.f;
    const int bm = node4 - ((ixg > 0) ? 48 : 0);
    const int bc = node4;
    const int bp = node4 + ((ixg < GRIDW - 1) ? 48 : 0);
    const int nx = 1 + (ixg > 0) + (ixg < GRIDW - 1);

    // coefficients -> registers
    float gxr[3][3];
    f32x4 wymv[3], wypv[3];
    float wycv[3];
#pragma unroll
    for (int k = 0; k < 3; ++k) {
#pragma unroll
        for (int xc = 0; xc < 3; ++xc) gxr[xc][k] = gxs[xc][k];
        const float g0 = gys[0][k], g1 = gys[1][k], g2v = gys[2][k];
        wymv[k] = (f32x4){m0 * g0, g0, g0, g0};
        wycv[k] = g1;
        wypv[k] = (f32x4){g2v, g2v, g2v, m3 * g2v};
    }
    const int bases[3] = {bm, bc, bp};
    const float wxv[3] = {wxm, 1.f, wxp};

    f32x4 o[4];
#pragma unroll
    for (int j = 0; j < 4; ++j) o[j] = (f32x4){0.f, 0.f, 0.f, 0.f};

#pragma unroll
    for (int k = 0; k < 3; ++k) {
#pragma unroll
        for (int xc = 0; xc < 3; ++xc) {
            const float gw = gxr[xc][k] * wxv[xc];
            const int base = bases[xc];
#pragma unroll
            for (int j = 0; j < 4; ++j) {
                const unsigned short* pl =
                    TR2 + (size_t)(k * 44 + c0 + j) * NNODES;
                uint2 A  = *(const uint2*)(pl + base - dA);
                uint2 B  = *(const uint2*)(pl + base);
                uint2 Cc = *(const uint2*)(pl + base + dC);
                float a3 = bf2f((unsigned short)(A.y >> 16));
                float b0 = bf2f((unsigned short)(B.x & 0xFFFFu));
                float b1 = bf2f((unsigned short)(B.x >> 16));
                float b2 = bf2f((unsigned short)(B.y & 0xFFFFu));
                float b3 = bf2f((unsigned short)(B.y >> 16));
                float cv = bf2f((unsigned short)(Cc.x & 0xFFFFu));
                f32x4 vm = (f32x4){a3, b0, b1, b2};
                f32x4 vc = (f32x4){b0, b1, b2, b3};
                f32x4 vp = (f32x4){b1, b2, b3, cv};
                f32x4 u = wymv[k] * vm + wycv[k] * vc + wypv[k] * vp;
                o[j] += gw * u;
            }
        }
    }

    // per-element 1/deg
    const int ny0 = 1 + ((y0 > 0) ? 1 : 0) + 1;          // y0 elem: y<47 always
    const int ny3 = 1 + 1 + ((y0 + 3 < GRIDW - 1) ? 1 : 0);
    const float i3 = 1.f / (float)(3 * nx);
    const f32x4 invv = (f32x4){1.f / (float)(nx * ny0), i3, i3,
                               1.f / (float)(nx * ny3)};

    float sj[4], qj[4];
#pragma unroll
    for (int j = 0; j < 4; ++j) {
        o[j] = o[j] * invv;
        uint2 rv = *(const uint2*)(TR2 + (size_t)(132 + c0 + j) * NNODES + node4);
        o[j] += b2v(rv);
        unsigned lo = (unsigned)f2bf(o[j].x) | ((unsigned)f2bf(o[j].y) << 16);
        unsigned hi = (unsigned)f2bf(o[j].z) | ((unsigned)f2bf(o[j].w) << 16);
        *(uint2*)(C2 + (size_t)(c0 + j) * NNODES + node4) = make_uint2(lo, hi);
        sj[j] = o[j].x + o[j].y + o[j].z + o[j].w;
        qj[j] = o[j].x * o[j].x + o[j].y * o[j].y
              + o[j].z * o[j].z + o[j].w * o[j].w;
    }

    // wave-level stats reduce (og uniform per wave) -> 8 atomics per wave
    const int lane = tid & 63;
#pragma unroll
    for (int j = 0; j < 4; ++j) {
        float sv = sj[j], qv = qj[j];
        sv += __shfl_down(sv, 32); qv += __shfl_down(qv, 32);
        sv += __shfl_down(sv, 16); qv += __shfl_down(qv, 16);
        sv += __shfl_down(sv, 8);  qv += __shfl_down(qv, 8);
        sv += __shfl_down(sv, 4);  qv += __shfl_down(qv, 4);
        sv += __shfl_down(sv, 2);  qv += __shfl_down(qv, 2);
        sv += __shfl_down(sv, 1);  qv += __shfl_down(qv, 1);
        if (lane == 0) {
            const int sh = wg & (NSH - 1);
            atomicAdd(&sum2[sh * SHS + c0 + j], sv);
            atomicAdd(&ss2[sh * SHS + c0 + j], qv);
        }
    }
}

// ---------------------------------------------------------------------------
extern "C" void kernel_launch(void* const* d_in, const int* in_sizes, int n_in,
                              void* d_out, int out_size, void* d_ws, size_t ws_size,
                              hipStream_t stream) {
    const float* x      = (const float*)d_in[0];
    const float* w0     = (const float*)d_in[3];
    const float* b0     = (const float*)d_in[4];
    const float* gamma0 = (const float*)d_in[5];
    const float* beta0  = (const float*)d_in[6];
    const float* w1     = (const float*)d_in[7];
    const float* b1     = (const float*)d_in[8];
    const float* gamma1 = (const float*)d_in[9];
    const float* beta1  = (const float*)d_in[10];
    const float* w2     = (const float*)d_in[11];
    const float* g2     = (const float*)d_in[12];
    const float* mu2    = (const float*)d_in[13];
    const float* sigma2 = (const float*)d_in[14];
    const float* b2     = (const float*)d_in[15];
    const float* gamma2 = (const float*)d_in[16];
    const float* beta2  = (const float*)d_in[17];
    const float* w3     = (const float*)d_in[18];
    const float* b3     = (const float*)d_in[19];
    float* out = (float*)d_out;

    const int N = NNODES;
    const float invN = 1.0f / (float)N;

    // [0,44N): Y1 bf16 (40N f-eq) then C2 channel-major 48 planes (24N f-eq)
    // [44N,132N): Y0 bf16 (56N f-eq) then TR2 channel-major 176 planes (88N)
    const size_t tailOff = (size_t)N * 132;
    size_t need = (tailOff + 300000) * sizeof(float);
    if (ws_size < need) return;

    float* ws = (float*)d_ws;
    unsigned short* bufY1 = (unsigned short*)ws;
    unsigned short* bufC  = (unsigned short*)ws;
    unsigned short* bufY0 = (unsigned short*)(ws + (size_t)N * 44);
    unsigned short* bufTR = bufY0;

    float* tail = ws + tailOff;
    // 6 stat arrays x 8 shadows x 128 stride = 6144 floats
    float* sum0 = tail;                 // 1024
    float* ss0  = tail + 1024;          // 1024
    float* sum1 = tail + 2048;          // 1024
    float* ss1  = tail + 3072;          // 1024
    float* sum2 = tail + 4096;          // 1024
    float* ss2  = tail + 5120;          // 1024
    float* biasf0 = tail + 6144;        // 112
    float* biasf1 = tail + 6256;        // 80
    float* biasf2 = tail + 6336;        // 176
    float* biasf3 = tail + 6512;        // 16
    unsigned short* wt0 = (unsigned short*)(tail + 6528);   // 112*128
    unsigned short* wt1 = wt0 + 14336;                      // 80*128
    unsigned short* wt2 = wt1 + 10240;                      // 176*96
    unsigned short* wt3 = wt2 + 16896;                      // 16*64

    // prep re-zeros the stat shadows each replay (graph-safe).
    prep<<<192, 256, 0, stream>>>(w0, b0, w1, b1, g2, w2, b2, w3, b3,
                                  wt0, wt1, wt2, wt3,
                                  biasf0, biasf1, biasf2, biasf3, tail);

    // L0: Y0 = x @ w0 + b0 (bf16 out, stats -> sum0/ss0 shadows)
    gemm_p<128, 128, 112, 102, 0, 0, true, true, false, false, false>
        <<<GB, 256, 0, stream>>>(
        x, wt0, biasf0, nullptr, nullptr, nullptr, nullptr, invN, bufY0, sum0, ss0);

    // L1: Y1 = BN0(Y0) @ w1 + b1 (BN on A-side; stats -> sum1/ss1 shadows)
    gemm_p<112, 128, 80, 73, 102, 1, true, true, true, false, false>
        <<<GB, 256, 0, stream>>>(
        bufY0, wt1, biasf1, sum0, ss0, gamma0, beta0, invN, bufY1, sum1, ss1);

    // L2: TR2 = BN1(Y1) @ [g2 | w2] (+[0|b2]), 176 wide, CHANNEL-MAJOR out
    gemm_p<80, 96, 176, 176, 73, 1, false, true, true, true, false>
        <<<GB, 256, 0, stream>>>(
        bufY1, wt2, biasf2, sum1, ss1, gamma1, beta1, invN, bufTR, nullptr, nullptr);

    // y-vectorized channel-major stencil: C2 planes = r + agg(t)/deg
    gmm_stencil<<<1584, 256, 0, stream>>>(bufTR, bufC, mu2, sigma2, sum2, ss2);

    // L3: out = BN2(C2) @ w3 + b3 (fp32 out; ACM staging; BN from shadows)
    gemm_p<48, 64, 16, 16, 44, 1, false, false, true, false, true>
        <<<GB, 256, 0, stream>>>(
        bufC, wt3, biasf3, sum2, ss2, gamma2, beta2, invN, out, nullptr, nullptr);
}